// Round 7
// baseline (147.362 us; speedup 1.0000x reference)
//
#include <hip/hip_runtime.h>
#include <hip/hip_bf16.h>
#include <stdint.h>

// FGN layer: out = (x@W^T + bias) * exp(-( x^2@ic2^T + x@(-2c*ic2)^T + d ))
// R6 post-mortem: GEMM was LDS-bandwidth-bound (~96-144 KB/CU/slab vs 775
// MFMA-cyc). R7: LDS-FREE GEMM. prep writes all 4 streams in MFMA-fragment
// order so each fragment is ONE lane-linear global_load_dwordx4 (L1/L2-hot
// panels). No barriers in the K-loop; register double-buffer, compiler
// vmcnt pipelining. 512 thr = 2 kg x (2m x 2n) waves, wave tile 64x64,
// block 128x128, grid (32,8). kg-partials reduced via conflict-free LDS
// epilogue ([r][lane] layout).

typedef __attribute__((ext_vector_type(8))) __bf16 bf16x8;
typedef __attribute__((ext_vector_type(4))) float f32x4;
typedef __attribute__((ext_vector_type(16))) float f32x16;

#define G_SCALE 8388608.0f    /* 2^23 */
#define G_INV   1.1920929e-7f /* 2^-23 */

__device__ __forceinline__ unsigned int f2bf(float f) {
  union { float f; unsigned int u; } v; v.f = f;
  unsigned int u = v.u;
  return (u + 0x7FFFu + ((u >> 16) & 1u)) >> 16;  // RNE
}

__device__ __forceinline__ uint4 pack8bf(const float* v) {
  uint4 r;
  r.x = f2bf(v[0]) | (f2bf(v[1]) << 16);
  r.y = f2bf(v[2]) | (f2bf(v[3]) << 16);
  r.z = f2bf(v[4]) | (f2bf(v[5]) << 16);
  r.w = f2bf(v[6]) | (f2bf(v[7]) << 16);
  return r;
}

// fp8 e4m3fn encode, RNE, FTZ below 2^-6 (irrelevant for G: delta_g < 1e-7)
__device__ __forceinline__ unsigned int f2f8(float f) {
  union { float f; unsigned int u; } v; v.f = f;
  unsigned int u = v.u;
  unsigned int s = (u >> 31) << 7;
  unsigned int e = (u >> 23) & 255u;
  if (e < 121u) return s;
  unsigned int q = ((e - 120u) << 23) | (u & 0x7FFFFFu);
  unsigned int r = (q + 0x7FFFFu + ((q >> 20) & 1u)) >> 20;
  if (r > 126u) r = 126u;
  return s | r;
}

__device__ __forceinline__ unsigned long long pack8f8(const float* x) {
  unsigned long long r = 0;
#pragma unroll
  for (int j = 0; j < 8; ++j) r |= (unsigned long long)f2f8(x[j]) << (8 * j);
  return r;
}

// Fragment-order layout, 16B chunk (row, k8) -> uint4 index
//   ((row>>5)*64 + (k8>>1))*64 + (k8&1)*32 + (row&31)
// so fragment (blk, ksg) is uint4[(blk*64+ksg)*64 + lane], lane-linear.
// blocks 0..1023: W rows (4/block, wave each): Wf bf16, GBf=[fp8(ic2*2^23)|
// fp8(-2c*ic2*2^23)]; bias=-sum W*C, d=sum C^2*ic2 (fp32).
// blocks 1024..1279: x rows: Xf bf16, XQf=[fp8(x^2)|fp8(x)].
__global__ __launch_bounds__(256) void prep(
    const float* __restrict__ X, const float* __restrict__ W,
    const float* __restrict__ C, const float* __restrict__ IC,
    uint4* __restrict__ Wf, ulonglong2* __restrict__ GBf,
    uint4* __restrict__ Xf, ulonglong2* __restrict__ XQf,
    float* __restrict__ bias, float* __restrict__ dvec) {
  const int b = blockIdx.x;
  const int lane = threadIdx.x & 63;   // lane == ksg (16 elems each)
  if (b < 1024) {
    const int row = b * 4 + (threadIdx.x >> 6);
    const float4* W4 = (const float4*)W + (size_t)row * 256 + lane * 4;
    const float4* C4 = (const float4*)C + (size_t)row * 256 + lane * 4;
    const float4* I4 = (const float4*)IC + (size_t)row * 256 + lane * 4;
    float wv[16], cv[16], i2[16], i2s[16], m2[16];
    float swc = 0.f, sd = 0.f;
#pragma unroll
    for (int p = 0; p < 4; ++p) {
      float4 w = W4[p], c = C4[p], ic = I4[p];
      wv[4*p] = w.x; wv[4*p+1] = w.y; wv[4*p+2] = w.z; wv[4*p+3] = w.w;
      cv[4*p] = c.x; cv[4*p+1] = c.y; cv[4*p+2] = c.z; cv[4*p+3] = c.w;
      i2[4*p] = ic.x*ic.x; i2[4*p+1] = ic.y*ic.y;
      i2[4*p+2] = ic.z*ic.z; i2[4*p+3] = ic.w*ic.w;
    }
#pragma unroll
    for (int j = 0; j < 16; ++j) {
      swc += wv[j] * cv[j];
      sd  += cv[j] * cv[j] * i2[j];
      i2s[j] = i2[j] * G_SCALE;
      m2[j]  = -2.f * cv[j] * i2[j] * G_SCALE;
    }
    const size_t idx = ((size_t)(row >> 5) * 64 + lane) * 64 + (row & 31);
    Wf[idx]      = pack8bf(wv);
    Wf[idx + 32] = pack8bf(wv + 8);
    ulonglong2 g0, g1;
    g0.x = pack8f8(i2s);     g0.y = pack8f8(m2);
    g1.x = pack8f8(i2s + 8); g1.y = pack8f8(m2 + 8);
    GBf[idx] = g0; GBf[idx + 32] = g1;
#pragma unroll
    for (int off = 32; off > 0; off >>= 1) {
      swc += __shfl_down(swc, off);
      sd  += __shfl_down(sd, off);
    }
    if (lane == 0) { bias[row] = -swc; dvec[row] = sd; }
  } else {
    const int row = (b - 1024) * 4 + (threadIdx.x >> 6);
    const float4* X4 = (const float4*)X + (size_t)row * 256 + lane * 4;
    float xv[16], qv[16];
#pragma unroll
    for (int p = 0; p < 4; ++p) {
      float4 x = X4[p];
      xv[4*p] = x.x; xv[4*p+1] = x.y; xv[4*p+2] = x.z; xv[4*p+3] = x.w;
    }
#pragma unroll
    for (int j = 0; j < 16; ++j) qv[j] = xv[j] * xv[j];
    const size_t idx = ((size_t)(row >> 5) * 64 + lane) * 64 + (row & 31);
    Xf[idx]      = pack8bf(xv);
    Xf[idx + 32] = pack8bf(xv + 8);
    ulonglong2 q0, q1;
    q0.x = pack8f8(qv);     q0.y = pack8f8(xv);
    q1.x = pack8f8(qv + 8); q1.y = pack8f8(xv + 8);
    XQf[idx] = q0; XQf[idx + 32] = q1;
  }
}

// LDS-free GEMM. 512 thr = 8 waves: kg = wave>>2 (K half), wy=(wave>>1)&1,
// wx=wave&1. Wave tile 64Mx64N = 2x2 frags of 32x32. Each fragment load is
// one lane-linear global_load_dwordx4 from the fragment-order streams.
// No barriers in the K-loop; register double-buffer, full unroll.
__global__ __launch_bounds__(512, 2) void fgn_gemm(
    const uint4* __restrict__ Xf, const uint4* __restrict__ XQf,
    const uint4* __restrict__ Wf, const uint4* __restrict__ GBf,
    const float* __restrict__ bias, const float* __restrict__ dvec,
    float* __restrict__ out) {
  __shared__ float red[16384];    // 64 KB, epilogue kg-reduction only
  const int t = threadIdx.x;
  const int wave = t >> 6, lane = t & 63;
  const int kg = wave >> 2, wy = (wave >> 1) & 1, wx = wave & 1;
  const int mb0 = blockIdx.y * 4 + wy * 2;   // 32-row m blocks
  const int nb0 = blockIdx.x * 4 + wx * 2;   // 32-row n blocks

  const uint4 *pa[2], *pq[2], *pw[2], *pg[2];
#pragma unroll
  for (int i = 0; i < 2; ++i) {
    const size_t ai = ((size_t)(mb0 + i) * 64 + kg * 32) * 64 + lane;
    const size_t bi = ((size_t)(nb0 + i) * 64 + kg * 32) * 64 + lane;
    pa[i] = Xf + ai;  pq[i] = XQf + ai;
    pw[i] = Wf + bi;  pg[i] = GBf + bi;
  }

  f32x16 accL[2][2], accG[2][2];
#pragma unroll
  for (int i = 0; i < 2; ++i)
#pragma unroll
    for (int j = 0; j < 2; ++j) { accL[i][j] = (f32x16)0.f; accG[i][j] = (f32x16)0.f; }

  uint4 ax0[2], xq0[2], bw0[2], gb0[2];
#pragma unroll
  for (int i = 0; i < 2; ++i) {
    ax0[i] = pa[i][0]; xq0[i] = pq[i][0];
    bw0[i] = pw[i][0]; gb0[i] = pg[i][0];
    pa[i] += 64; pq[i] += 64; pw[i] += 64; pg[i] += 64;
  }

#define COMPUTE(AX, XQ, BW, GB)                                                \
  do {                                                                         \
    _Pragma("unroll")                                                          \
    for (int i = 0; i < 2; ++i) {                                              \
      bf16x8 a = __builtin_bit_cast(bf16x8, (AX)[i]);                          \
      long2 q  = __builtin_bit_cast(long2, (XQ)[i]);                           \
      _Pragma("unroll")                                                        \
      for (int j = 0; j < 2; ++j) {                                            \
        bf16x8 w = __builtin_bit_cast(bf16x8, (BW)[j]);                        \
        long2 g  = __builtin_bit_cast(long2, (GB)[j]);                         \
        accL[i][j] = __builtin_amdgcn_mfma_f32_32x32x16_bf16(a, w, accL[i][j], 0, 0, 0); \
        accG[i][j] = __builtin_amdgcn_mfma_f32_32x32x16_fp8_fp8(q.x, g.x, accG[i][j], 0, 0, 0); \
        accG[i][j] = __builtin_amdgcn_mfma_f32_32x32x16_fp8_fp8(q.y, g.y, accG[i][j], 0, 0, 0); \
      }                                                                        \
    }                                                                          \
  } while (0)

#pragma unroll
  for (int s = 0; s < 31; ++s) {
    uint4 ax1[2], xq1[2], bw1[2], gb1[2];
#pragma unroll
    for (int i = 0; i < 2; ++i) {
      ax1[i] = pa[i][0]; xq1[i] = pq[i][0];
      bw1[i] = pw[i][0]; gb1[i] = pg[i][0];
      pa[i] += 64; pq[i] += 64; pw[i] += 64; pg[i] += 64;
    }
    COMPUTE(ax0, xq0, bw0, gb0);
#pragma unroll
    for (int i = 0; i < 2; ++i) {
      ax0[i] = ax1[i]; xq0[i] = xq1[i]; bw0[i] = bw1[i]; gb0[i] = gb1[i];
    }
  }
  COMPUTE(ax0, xq0, bw0, gb0);

  // ---- epilogue: kg=1 partials -> kg=0 via LDS ([r][lane]: conflict-free),
  // then bias/exp/store.
  f32x4* slot = (f32x4*)(red + (size_t)(wy * 2 + wx) * 4096);
  // round 1: accL
  if (kg == 1) {
#pragma unroll
    for (int i = 0; i < 2; ++i)
#pragma unroll
      for (int j = 0; j < 2; ++j) {
        const int fr = i * 2 + j;
#pragma unroll
        for (int r = 0; r < 4; ++r) {
          f32x4 c = { accL[i][j][4*r], accL[i][j][4*r+1],
                      accL[i][j][4*r+2], accL[i][j][4*r+3] };
          slot[fr * 256 + r * 64 + lane] = c;
        }
      }
  }
  __syncthreads();
  if (kg == 0) {
#pragma unroll
    for (int i = 0; i < 2; ++i)
#pragma unroll
      for (int j = 0; j < 2; ++j) {
        const int fr = i * 2 + j;
#pragma unroll
        for (int r = 0; r < 4; ++r) {
          f32x4 c = slot[fr * 256 + r * 64 + lane];
          accL[i][j][4*r]   += c[0]; accL[i][j][4*r+1] += c[1];
          accL[i][j][4*r+2] += c[2]; accL[i][j][4*r+3] += c[3];
        }
      }
  }
  __syncthreads();
  // round 2: accG
  if (kg == 1) {
#pragma unroll
    for (int i = 0; i < 2; ++i)
#pragma unroll
      for (int j = 0; j < 2; ++j) {
        const int fr = i * 2 + j;
#pragma unroll
        for (int r = 0; r < 4; ++r) {
          f32x4 c = { accG[i][j][4*r], accG[i][j][4*r+1],
                      accG[i][j][4*r+2], accG[i][j][4*r+3] };
          slot[fr * 256 + r * 64 + lane] = c;
        }
      }
  }
  __syncthreads();
  if (kg == 0) {
    const int ln = lane & 31, kh = lane >> 5;
#pragma unroll
    for (int j = 0; j < 2; ++j) {
      const int col = (nb0 + j) * 32 + ln;
      const float bn = bias[col], dn = dvec[col];
#pragma unroll
      for (int i = 0; i < 2; ++i) {
        const int fr = i * 2 + j;
        f32x16 gacc = accG[i][j];
#pragma unroll
        for (int r = 0; r < 4; ++r) {
          f32x4 c = slot[fr * 256 + r * 64 + lane];
          gacc[4*r]   += c[0]; gacc[4*r+1] += c[1];
          gacc[4*r+2] += c[2]; gacc[4*r+3] += c[3];
        }
        // C/D 32x32 layout: col=lane&31, row=(reg&3)+8*(reg>>2)+4*(lane>>5)
        const int rb = (mb0 + i) * 32 + 4 * kh;
#pragma unroll
        for (int r = 0; r < 16; ++r) {
          const int row = rb + (r & 3) + 8 * (r >> 2);
          const float l = accL[i][j][r] + bn;
          const float g = gacc[r] * G_INV + dn;
          out[(size_t)row * 4096 + col] = l * __expf(-g);
        }
      }
    }
  }
#undef COMPUTE
}

extern "C" void kernel_launch(void* const* d_in, const int* in_sizes, int n_in,
                              void* d_out, int out_size, void* d_ws, size_t ws_size,
                              hipStream_t stream) {
  const float* x  = (const float*)d_in[0];
  const float* W  = (const float*)d_in[1];
  const float* C  = (const float*)d_in[2];
  const float* IC = (const float*)d_in[3];
  float* out = (float*)d_out;

  char* ws = (char*)d_ws;
  uint4*      Wf  = (uint4*)(ws);                     // 8 MB bf16 W frag-order
  ulonglong2* GBf = (ulonglong2*)(ws + (8u << 20));   // 8 MB [ic2'|m2'] fp8
  uint4*      Xf  = (uint4*)(ws + (16u << 20));       // 2 MB bf16 x
  ulonglong2* XQf = (ulonglong2*)(ws + (18u << 20));  // 2 MB [x^2|x] fp8
  float* bias = (float*)(ws + (20u << 20));           // 16 KB
  float* dvec = (float*)(ws + (20u << 20) + 16384);   // 16 KB

  hipLaunchKernelGGL(prep, dim3(1280), dim3(256), 0, stream, x, W, C, IC,
                     Wf, GBf, Xf, XQf, bias, dvec);
  hipLaunchKernelGGL(fgn_gemm, dim3(32, 8), dim3(512), 0, stream,
                     Xf, (const uint4*)XQf, Wf, (const uint4*)GBf,
                     bias, dvec, out);
}